// Round 1
// baseline (46.439 us; speedup 1.0000x reference)
//
#include <hip/hip_runtime.h>

// Output: (B,H,W,2) fp32 where
//   dy = p0 - y; dx = p1 - x; sq = dy^2 + dx^2
//   s  = tau * exp(-sq/sig^2) / sqrt(sq)
//   out = (s*dx, -s*dy)
// B=64, H=W=512. Per-batch pixel-pair (float4) count = 512*512/2 = 131072 = 1<<17.

__global__ __launch_bounds__(256) void vortex_velocity_kernel(
    const float* __restrict__ vf,    // [B][6]
    const float4* __restrict__ pts,  // [B*H*W/2] (two pixels per float4)
    float4* __restrict__ out,        // same layout
    int n4)
{
    const int stride = gridDim.x * blockDim.x;
    for (int i = blockIdx.x * blockDim.x + threadIdx.x; i < n4; i += stride) {
        const int b = i >> 17;                 // H*W/2 = 131072 float4 per batch
        const float y   = vf[b * 6 + 0];
        const float x   = vf[b * 6 + 1];
        const float tau = vf[b * 6 + 2];
        const float sig = vf[b * 6 + 3];
        const float inv_s2 = 1.0f / (sig * sig);

        const float4 p = pts[i];
        float4 o;

        // pixel 0
        {
            const float d1 = p.x - y;
            const float d2 = p.y - x;
            const float sq = d1 * d1 + d2 * d2;
            const float s  = tau * __expf(-sq * inv_s2) * rsqrtf(sq);
            o.x = s * d2;
            o.y = -s * d1;
        }
        // pixel 1
        {
            const float d1 = p.z - y;
            const float d2 = p.w - x;
            const float sq = d1 * d1 + d2 * d2;
            const float s  = tau * __expf(-sq * inv_s2) * rsqrtf(sq);
            o.z = s * d2;
            o.w = -s * d1;
        }
        out[i] = o;
    }
}

extern "C" void kernel_launch(void* const* d_in, const int* in_sizes, int n_in,
                              void* d_out, int out_size, void* d_ws, size_t ws_size,
                              hipStream_t stream) {
    const float*  vf  = (const float*)d_in[0];   // (64,1,6)
    const float4* pts = (const float4*)d_in[1];  // (64,512,512,2) -> float4 pairs
    float4* out = (float4*)d_out;

    const int n4 = out_size / 4;                 // 64*512*512*2/4 = 8388608
    const int block = 256;
    int grid = (n4 + block - 1) / block;
    if (grid > 2048) grid = 2048;                // 256 CU x 8 blocks, grid-stride rest

    vortex_velocity_kernel<<<grid, block, 0, stream>>>(vf, pts, out, n4);
}

// Round 3
// 42.379 us; speedup vs baseline: 1.0958x; 1.0958x over previous
//
#include <hip/hip_runtime.h>

// Output: (B,H,W,2) fp32 where
//   dy = p0 - y; dx = p1 - x; sq = dy^2 + dx^2
//   s  = tau * exp(-sq/sig^2) / sqrt(sq)
//   out = (s*dx, -s*dy)
// B=64, H=W=512. Per-batch float4 (pixel-pair) count = 512*512/2 = 131072 = 1<<17.
//
// R1 notes: 46.4us, FETCH=67MB (L3 absorbed half the input), WRITE=134MB.
// R2: nontemporal stores (write stream must not evict `points` from 256MB L3)
//     + exact grid, one float4/thread. Use a native clang ext_vector_type for
//     the nt store — the builtin rejects HIP_vector_type.

typedef float floatx4 __attribute__((ext_vector_type(4)));

__global__ __launch_bounds__(256) void vortex_velocity_kernel(
    const float* __restrict__ vf,      // [B][6]
    const floatx4* __restrict__ pts,   // [B*H*W/2]
    floatx4* __restrict__ out,
    int n4)
{
    const int i = blockIdx.x * blockDim.x + threadIdx.x;
    if (i >= n4) return;

    const int b = i >> 17;                 // H*W/2 = 131072 float4 per batch
    const float y   = vf[b * 6 + 0];
    const float x   = vf[b * 6 + 1];
    const float tau = vf[b * 6 + 2];
    const float sig = vf[b * 6 + 3];
    const float inv_s2 = 1.0f / (sig * sig);

    const floatx4 p = pts[i];
    floatx4 o;

    // pixel 0
    {
        const float d1 = p.x - y;
        const float d2 = p.y - x;
        const float sq = d1 * d1 + d2 * d2;
        const float s  = tau * __expf(-sq * inv_s2) * rsqrtf(sq);
        o.x = s * d2;
        o.y = -s * d1;
    }
    // pixel 1
    {
        const float d1 = p.z - y;
        const float d2 = p.w - x;
        const float sq = d1 * d1 + d2 * d2;
        const float s  = tau * __expf(-sq * inv_s2) * rsqrtf(sq);
        o.z = s * d2;
        o.w = -s * d1;
    }

    __builtin_nontemporal_store(o, &out[i]);
}

extern "C" void kernel_launch(void* const* d_in, const int* in_sizes, int n_in,
                              void* d_out, int out_size, void* d_ws, size_t ws_size,
                              hipStream_t stream) {
    const float*   vf  = (const float*)d_in[0];    // (64,1,6)
    const floatx4* pts = (const floatx4*)d_in[1];  // (64,512,512,2)
    floatx4* out = (floatx4*)d_out;

    const int n4 = out_size / 4;                   // 8388608
    const int block = 256;
    const int grid = (n4 + block - 1) / block;     // 32768 blocks

    vortex_velocity_kernel<<<grid, block, 0, stream>>>(vf, pts, out, n4);
}